// Round 4
// baseline (65.454 us; speedup 1.0000x reference)
//
#include <hip/hip_runtime.h>

// 6-qubit statevector, real arithmetic. RY-only circuit: state stays real;
// the CCC-Y block touches only the isolated q3q4q5=111 sector and reduces to
// a sign+reversal lane permutation (global phase i drops out of |.|^2).
//
// Layout: 8 lanes per batch element.
//   lane  = q0*4 + q1*2 + q2   (lane bits: q0->4, q1->2, q2->1)
//   reg r = q3*4 + q4*2 + q5   (st[0..7] register-resident)
// Gates targeting q3/q4/q5: in-register pair updates (controls on q0..2 fold
// into per-lane coefficients; controls on q3..5 restrict pairs statically).
// Gates targeting q0/q1/q2: cross-lane via DPP (xor1/xor2/xor7) or ds_swizzle
// (xor4). DPP is full-rate VALU, no LDS pipe.
//
// Round 4: __sincosf replaced with __sinf/__cosf — HIP's __sincosf can lower
// to the precise ocml sincos (~60-100 VALU instrs w/ range reduction); 36 of
// those ~= the entire unexplained 20 us residual. __sinf/__cosf are the
// guaranteed-native v_sin_f32/v_cos_f32 path (~3 instrs each).

template <int XM>
__device__ __forceinline__ float lane_perm(float v) {
    int i = __float_as_int(v);
    int r;
    if constexpr (XM == 1)
        r = __builtin_amdgcn_update_dpp(i, i, 0xB1, 0xF, 0xF, 0);  // quad_perm [1,0,3,2]
    else if constexpr (XM == 2)
        r = __builtin_amdgcn_update_dpp(i, i, 0x4E, 0xF, 0xF, 0);  // quad_perm [2,3,0,1]
    else if constexpr (XM == 4)
        r = __builtin_amdgcn_ds_swizzle(i, 0x101F);                // xor 4
    else
        r = __builtin_amdgcn_update_dpp(i, i, 0x141, 0xF, 0xF, 0); // row_half_mirror = xor7
    return __int_as_float(r);
}

template <int TB, int CB>  // in-register gate: target bit, control bit (0=none)
__device__ __forceinline__ void ry_r(float* st, float c, float s) {
#pragma unroll
    for (int r = 0; r < 8; ++r) {
        if (r & TB) continue;
        if (CB && !(r & CB)) continue;
        float a0 = st[r], a1 = st[r + TB];
        st[r]      = fmaf(c, a0, -(s * a1));
        st[r + TB] = fmaf(s, a0, c * a1);
    }
}

template <int TB, int LCM>  // in-register gate with lane (q0..2) control
__device__ __forceinline__ void gate_r(float* st, int lane, float c, float s) {
    if (LCM) {
        bool act = (lane & LCM) == LCM;
        c = act ? c : 1.0f;
        s = act ? s : 0.0f;
    }
    ry_r<TB, 0>(st, c, s);
}

template <int XM, int LCM>  // cross-lane gate (target in q0..2), optional lane control
__device__ __forceinline__ void gate_x(float* st, int lane, float c, float s) {
    float ssgn = (lane & XM) ? s : -s;  // bit0 side: c*a0 - s*a1 ; bit1: s*a0 + c*a1
    if (LCM) {
        bool act = (lane & LCM) == LCM;
        c = act ? c : 1.0f;
        ssgn = act ? ssgn : 0.0f;
    }
#pragma unroll
    for (int r = 0; r < 8; ++r) {
        float pr = lane_perm<XM>(st[r]);
        st[r] = fmaf(c, st[r], ssgn * pr);
    }
}

__global__ __launch_bounds__(256) void pnn_kernel(const float* __restrict__ x,
                                                  const float* __restrict__ p,
                                                  float* __restrict__ out,
                                                  int n) {
    int gtid = blockIdx.x * blockDim.x + threadIdx.x;
    int e = gtid >> 3;
    int lane = gtid & 7;
    if (e >= n) return;
    float xv = x[e];

    float st[8];
#pragma unroll
    for (int r = 0; r < 8; ++r) st[r] = 0.0f;
    if (lane == 0) st[0] = 1.0f;

    float c, s;
    auto cs = [&](float th) {  // native v_sin_f32/v_cos_f32 path
        float h = th * 0.5f;
        s = __sinf(h);
        c = __cosf(h);
    };

    // -- block 1: encoding + variational fused (targets q0,q1,q2) --
    cs(fmaf(xv, 3.0f, p[0])); gate_x<4, 0>(st, lane, c, s);
    cs(fmaf(xv, 9.0f, p[1])); gate_x<2, 0>(st, lane, c, s);
    cs(xv + p[2]);            gate_x<1, 0>(st, lane, c, s);
    // -- controlled rotations onto q3 (TB=4); lane controls q2->1, q1->2, q0->4
    cs(p[3]);        gate_r<4, 1>(st, lane, c, s);
    cs(p[4]);        gate_r<4, 2>(st, lane, c, s);
    cs(p[5]);        gate_r<4, 4>(st, lane, c, s);
    cs(p[6] + 0.5f); ry_r<4, 0>(st, c, s);        // RY(p6) fused with RY(0.5)
    // -- q4 (TB=2) --
    cs(p[7]);         gate_r<2, 1>(st, lane, c, s);
    cs(p[8]);         gate_r<2, 2>(st, lane, c, s);
    cs(p[9]);         gate_r<2, 4>(st, lane, c, s);
    cs(p[10] + 0.5f); ry_r<2, 0>(st, c, s);
    // -- q5 (TB=1) --
    cs(p[11]);        gate_r<1, 1>(st, lane, c, s);
    cs(p[12]);        gate_r<1, 2>(st, lane, c, s);
    cs(p[13]);        gate_r<1, 4>(st, lane, c, s);
    cs(p[14] + 0.5f); ry_r<1, 0>(st, c, s);
    // -- entangling block among q3,q4,q5 (register controls) --
    cs(p[15]); ry_r<2, 4>(st, c, s);  // t4 c3
    cs(p[16]); ry_r<1, 4>(st, c, s);  // t5 c3
    cs(p[17]); ry_r<4, 2>(st, c, s);  // t3 c4
    cs(p[18]); ry_r<1, 2>(st, c, s);  // t5 c4
    cs(p[19]); ry_r<4, 1>(st, c, s);  // t3 c5
    cs(p[20]); ry_r<2, 1>(st, c, s);  // t4 c5
    cs(p[21]); ry_r<4, 0>(st, c, s);
    cs(p[22]); ry_r<2, 0>(st, c, s);
    cs(p[23]); ry_r<1, 0>(st, c, s);

    // -- triply-controlled Y on q0,q1,q2: sector r=7 only.
    // new st[7](lane j) = (-1)^popcount(j) * old st[7](lane j^7); phase i drops.
    {
        float ysign = (__popc(lane) & 1) ? -1.0f : 1.0f;
        st[7] = ysign * lane_perm<7>(st[7]);
    }

    // -- block 2: encoding + variational + RY(-0.5), triple-fused --
    cs(fmaf(xv, 7.0f, p[24]) - 0.5f);  gate_x<4, 0>(st, lane, c, s);
    cs(fmaf(xv, 17.0f, p[25]) - 0.5f); gate_x<2, 0>(st, lane, c, s);
    cs(xv + p[26] - 0.5f);             gate_x<1, 0>(st, lane, c, s);
    // -- entangling block among q0,q1,q2 (lane controls) --
    cs(p[27]); gate_x<2, 4>(st, lane, c, s);  // t1 c0
    cs(p[28]); gate_x<1, 4>(st, lane, c, s);  // t2 c0
    cs(p[29]); gate_x<4, 2>(st, lane, c, s);  // t0 c1
    cs(p[30]); gate_x<1, 2>(st, lane, c, s);  // t2 c1
    cs(p[31]); gate_x<4, 1>(st, lane, c, s);  // t0 c2
    cs(p[32]); gate_x<2, 1>(st, lane, c, s);  // t1 c2
    cs(p[33]); gate_x<4, 0>(st, lane, c, s);
    cs(p[34]); gate_x<2, 0>(st, lane, c, s);
    cs(p[35]); gate_x<1, 0>(st, lane, c, s);

    // p000 = lane 0's sum of squares; p111 = lane 7's. Exchange via xor7 DPP.
    float psum = 0.0f;
#pragma unroll
    for (int r = 0; r < 8; ++r) psum = fmaf(st[r], st[r], psum);
    float other = lane_perm<7>(psum);  // lane0 <- lane7 (= p111)
    if (lane == 0) out[e] = (other - psum) * 2.0f;
}

extern "C" void kernel_launch(void* const* d_in, const int* in_sizes, int n_in,
                              void* d_out, int out_size, void* d_ws, size_t ws_size,
                              hipStream_t stream) {
    const float* x = (const float*)d_in[0];
    const float* p = (const float*)d_in[1];
    float* out = (float*)d_out;
    int n = in_sizes[0];
    long long threads = (long long)n * 8;
    int block = 256;
    int grid = (int)((threads + block - 1) / block);
    pnn_kernel<<<grid, block, 0, stream>>>(x, p, out, n);
}

// Round 5
// 60.980 us; speedup vs baseline: 1.0734x; 1.0734x over previous
//
#include <hip/hip_runtime.h>

// 6-qubit statevector, real arithmetic. RY-only circuit: state stays real;
// the CCC-Y block touches only the isolated q3q4q5=111 sector and reduces to
// a sign+reversal lane permutation (global phase i drops out of |.|^2).
//
// Layout: 8 lanes per batch element.
//   lane  = q0*4 + q1*2 + q2   (lane bits: q0->4, q1->2, q2->1)
//   reg r = q3*4 + q4*2 + q5   (st[0..7] register-resident)
// Gates targeting q3/q4/q5: in-register pair updates. Gates targeting
// q0/q1/q2: cross-lane via DPP (xor1/xor2/xor7) or ds_swizzle (xor4).
//
// Round 5:
//  (a) 30 of 36 rotation angles are batch-uniform (p-only). Their (cos,sin)
//      pairs are computed once per block by threads 0..29 into a 240 B LDS
//      table (broadcast ds_read at use) instead of per-thread sincos:
//      ~210 VALU instrs/thread -> ~30 ds_reads.
//  (b) cross-lane gate written as fmaf(ssgn, dpp(st), c*st) so the backend's
//      DPP-combine can fold the v_mov_b32_dpp into v_fmac_f32_dpp.
// Floor note: ~58 us of dur_us is harness re-poison fills (268 MB ws fill =
// 40 us alone) + graph overhead; kernel is ~7 us of the 65.5.

template <int XM>
__device__ __forceinline__ float lane_perm(float v) {
    int i = __float_as_int(v);
    int r;
    if constexpr (XM == 1)
        r = __builtin_amdgcn_update_dpp(i, i, 0xB1, 0xF, 0xF, 0);  // quad_perm [1,0,3,2]
    else if constexpr (XM == 2)
        r = __builtin_amdgcn_update_dpp(i, i, 0x4E, 0xF, 0xF, 0);  // quad_perm [2,3,0,1]
    else if constexpr (XM == 4)
        r = __builtin_amdgcn_ds_swizzle(i, 0x101F);                // xor 4
    else
        r = __builtin_amdgcn_update_dpp(i, i, 0x141, 0xF, 0xF, 0); // row_half_mirror = xor7
    return __int_as_float(r);
}

template <int TB, int CB>  // in-register gate: target bit, reg-control bit (0=none)
__device__ __forceinline__ void ry_r(float* st, float c, float s) {
#pragma unroll
    for (int r = 0; r < 8; ++r) {
        if (r & TB) continue;
        if (CB && !(r & CB)) continue;
        float a0 = st[r], a1 = st[r + TB];
        st[r]      = fmaf(c, a0, -(s * a1));
        st[r + TB] = fmaf(s, a0, c * a1);
    }
}

template <int TB, int LCM>  // in-register gate with lane (q0..2) control
__device__ __forceinline__ void gate_r(float* st, int lane, float c, float s) {
    if (LCM) {
        bool act = (lane & LCM) == LCM;
        c = act ? c : 1.0f;
        s = act ? s : 0.0f;
    }
    ry_r<TB, 0>(st, c, s);
}

template <int XM, int LCM>  // cross-lane gate (target in q0..2), optional lane control
__device__ __forceinline__ void gate_x(float* st, int lane, float c, float s) {
    float ssgn = (lane & XM) ? s : -s;  // bit0 side: c*a0 - s*a1 ; bit1: s*a0 + c*a1
    if (LCM) {
        bool act = (lane & LCM) == LCM;
        c = act ? c : 1.0f;
        ssgn = act ? ssgn : 0.0f;
    }
#pragma unroll
    for (int r = 0; r < 8; ++r) {
        float t = c * st[r];                           // reads old st[r]
        st[r] = fmaf(ssgn, lane_perm<XM>(st[r]), t);   // dpp-fusable fmac
    }
}

__global__ __launch_bounds__(256) void pnn_kernel(const float* __restrict__ x,
                                                  const float* __restrict__ p,
                                                  float* __restrict__ out,
                                                  int n) {
    // Batch-uniform (cos,sin) table, one entry per p-only gate, in order:
    //  [0..3]   q3 block:  p3, p4, p5, p6+0.5
    //  [4..7]   q4 block:  p7, p8, p9, p10+0.5
    //  [8..11]  q5 block:  p11,p12,p13,p14+0.5
    //  [12..20] entangle q3q4q5: p15..p23
    //  [21..29] entangle q0q1q2: p27..p35
    __shared__ float2 cs_tab[30];
    {
        int t = threadIdx.x;
        if (t < 30) {
            int pi = (t < 21) ? (t + 3) : (t + 6);
            float off = (t == 3 || t == 7 || t == 11) ? 0.5f : 0.0f;
            float h = (p[pi] + off) * 0.5f;
            cs_tab[t] = make_float2(__cosf(h), __sinf(h));
        }
    }
    __syncthreads();

    int gtid = blockIdx.x * blockDim.x + threadIdx.x;
    int e = gtid >> 3;
    int lane = gtid & 7;
    bool live = (e < n);
    int ee = live ? e : 0;
    float xv = x[ee];

    float st[8];
#pragma unroll
    for (int r = 0; r < 8; ++r) st[r] = 0.0f;
    if (lane == 0) st[0] = 1.0f;

    float c, s;
    auto cs = [&](float th) {  // native v_sin/v_cos
        float h = th * 0.5f;
        s = __sinf(h);
        c = __cosf(h);
    };
    auto tab = [&](int k) {
        float2 v = cs_tab[k];
        c = v.x;
        s = v.y;
    };

    // -- block 1: encoding + variational fused (targets q0,q1,q2; x-dep) --
    cs(fmaf(xv, 3.0f, p[0])); gate_x<4, 0>(st, lane, c, s);
    cs(fmaf(xv, 9.0f, p[1])); gate_x<2, 0>(st, lane, c, s);
    cs(xv + p[2]);            gate_x<1, 0>(st, lane, c, s);
    // -- controlled rotations onto q3 (TB=4); lane controls q2->1, q1->2, q0->4
    tab(0); gate_r<4, 1>(st, lane, c, s);
    tab(1); gate_r<4, 2>(st, lane, c, s);
    tab(2); gate_r<4, 4>(st, lane, c, s);
    tab(3); ry_r<4, 0>(st, c, s);        // p6 fused with RY(0.5)
    // -- q4 (TB=2) --
    tab(4); gate_r<2, 1>(st, lane, c, s);
    tab(5); gate_r<2, 2>(st, lane, c, s);
    tab(6); gate_r<2, 4>(st, lane, c, s);
    tab(7); ry_r<2, 0>(st, c, s);
    // -- q5 (TB=1) --
    tab(8);  gate_r<1, 1>(st, lane, c, s);
    tab(9);  gate_r<1, 2>(st, lane, c, s);
    tab(10); gate_r<1, 4>(st, lane, c, s);
    tab(11); ry_r<1, 0>(st, c, s);
    // -- entangling block among q3,q4,q5 (register controls) --
    tab(12); ry_r<2, 4>(st, c, s);  // t4 c3
    tab(13); ry_r<1, 4>(st, c, s);  // t5 c3
    tab(14); ry_r<4, 2>(st, c, s);  // t3 c4
    tab(15); ry_r<1, 2>(st, c, s);  // t5 c4
    tab(16); ry_r<4, 1>(st, c, s);  // t3 c5
    tab(17); ry_r<2, 1>(st, c, s);  // t4 c5
    tab(18); ry_r<4, 0>(st, c, s);
    tab(19); ry_r<2, 0>(st, c, s);
    tab(20); ry_r<1, 0>(st, c, s);

    // -- triply-controlled Y on q0,q1,q2: sector r=7 only.
    // new st[7](lane j) = (-1)^popcount(j) * old st[7](lane j^7); phase i drops.
    {
        float ysign = (__popc(lane) & 1) ? -1.0f : 1.0f;
        st[7] = ysign * lane_perm<7>(st[7]);
    }

    // -- block 2: encoding + variational + RY(-0.5), triple-fused (x-dep) --
    cs(fmaf(xv, 7.0f, p[24]) - 0.5f);  gate_x<4, 0>(st, lane, c, s);
    cs(fmaf(xv, 17.0f, p[25]) - 0.5f); gate_x<2, 0>(st, lane, c, s);
    cs(xv + p[26] - 0.5f);             gate_x<1, 0>(st, lane, c, s);
    // -- entangling block among q0,q1,q2 (lane controls) --
    tab(21); gate_x<2, 4>(st, lane, c, s);  // t1 c0
    tab(22); gate_x<1, 4>(st, lane, c, s);  // t2 c0
    tab(23); gate_x<4, 2>(st, lane, c, s);  // t0 c1
    tab(24); gate_x<1, 2>(st, lane, c, s);  // t2 c1
    tab(25); gate_x<4, 1>(st, lane, c, s);  // t0 c2
    tab(26); gate_x<2, 1>(st, lane, c, s);  // t1 c2
    tab(27); gate_x<4, 0>(st, lane, c, s);
    tab(28); gate_x<2, 0>(st, lane, c, s);
    tab(29); gate_x<1, 0>(st, lane, c, s);

    // p000 = lane 0's sum of squares; p111 = lane 7's. Exchange via xor7 DPP.
    float psum = 0.0f;
#pragma unroll
    for (int r = 0; r < 8; ++r) psum = fmaf(st[r], st[r], psum);
    float other = lane_perm<7>(psum);  // lane0 <- lane7 (= p111)
    if (live && lane == 0) out[e] = (other - psum) * 2.0f;
}

extern "C" void kernel_launch(void* const* d_in, const int* in_sizes, int n_in,
                              void* d_out, int out_size, void* d_ws, size_t ws_size,
                              hipStream_t stream) {
    const float* x = (const float*)d_in[0];
    const float* p = (const float*)d_in[1];
    float* out = (float*)d_out;
    int n = in_sizes[0];
    long long threads = (long long)n * 8;
    int block = 256;
    int grid = (int)((threads + block - 1) / block);
    pnn_kernel<<<grid, block, 0, stream>>>(x, p, out, n);
}

// Round 6
// 60.908 us; speedup vs baseline: 1.0746x; 1.0012x over previous
//
#include <hip/hip_runtime.h>

// 6-qubit statevector, real arithmetic. RY-only circuit: state stays real;
// the CCC-Y block touches only the isolated q3q4q5=111 sector and reduces to
// a sign+reversal lane permutation (global phase i drops out of |.|^2).
//
// Layout: 8 lanes per batch element.
//   lane  = q0*4 + q1*2 + q2   (lane bits: q0->4, q1->2, q2->1)
//   reg r = q3*4 + q4*2 + q5   (st[0..7] register-resident)
//
// Round 6: the 12 lane-controlled rotations onto q3/q4/q5 (p3..p14 + RY(0.5))
// are diagonal in the lane basis with a fixed target per block -> each block
// of 4 commutes and collapses to ONE rotation with per-lane summed angle:
//   theta3(lane) = p6+0.5 + (lane&1)*p3 + (lane&2)*p4 + (lane&4)*p5   (etc.)
// All 24 (c,s) pairs are (lane,p)-only -> precomputed in the per-block LDS
// table alongside the 18 batch-uniform entangling-gate pairs.
// Harness floor note: ~55-56 us of dur_us is re-poison fills (268 MB ws fill
// = 40 us alone) + graph overhead; kernel is ~4-5 us.

template <int XM>
__device__ __forceinline__ float lane_perm(float v) {
    int i = __float_as_int(v);
    int r;
    if constexpr (XM == 1)
        r = __builtin_amdgcn_update_dpp(i, i, 0xB1, 0xF, 0xF, 0);  // quad_perm [1,0,3,2]
    else if constexpr (XM == 2)
        r = __builtin_amdgcn_update_dpp(i, i, 0x4E, 0xF, 0xF, 0);  // quad_perm [2,3,0,1]
    else if constexpr (XM == 4)
        r = __builtin_amdgcn_ds_swizzle(i, 0x101F);                // xor 4
    else
        r = __builtin_amdgcn_update_dpp(i, i, 0x141, 0xF, 0xF, 0); // row_half_mirror = xor7
    return __int_as_float(r);
}

template <int TB, int CB>  // in-register gate: target bit, reg-control bit (0=none)
__device__ __forceinline__ void ry_r(float* st, float c, float s) {
#pragma unroll
    for (int r = 0; r < 8; ++r) {
        if (r & TB) continue;
        if (CB && !(r & CB)) continue;
        float a0 = st[r], a1 = st[r + TB];
        st[r]      = fmaf(c, a0, -(s * a1));
        st[r + TB] = fmaf(s, a0, c * a1);
    }
}

template <int XM, int LCM>  // cross-lane gate (target in q0..2), optional lane control
__device__ __forceinline__ void gate_x(float* st, int lane, float c, float s) {
    float ssgn = (lane & XM) ? s : -s;  // bit0 side: c*a0 - s*a1 ; bit1: s*a0 + c*a1
    if (LCM) {
        bool act = (lane & LCM) == LCM;
        c = act ? c : 1.0f;
        ssgn = act ? ssgn : 0.0f;
    }
#pragma unroll
    for (int r = 0; r < 8; ++r) {
        float t = c * st[r];                           // reads old st[r]
        st[r] = fmaf(ssgn, lane_perm<XM>(st[r]), t);   // dpp-fusable fmac
    }
}

__global__ __launch_bounds__(256) void pnn_kernel(const float* __restrict__ x,
                                                  const float* __restrict__ p,
                                                  float* __restrict__ out,
                                                  int n) {
    // LDS (cos,sin) table:
    //  [0..7]   fused q3-block angle per lane: p6+0.5 + sum of lane-controlled p3..p5
    //  [8..15]  fused q4-block angle per lane: p10+0.5 + p7..p9
    //  [16..23] fused q5-block angle per lane: p14+0.5 + p11..p13
    //  [24..32] entangle q3q4q5: p15..p23
    //  [33..41] entangle q0q1q2: p27..p35
    __shared__ float2 cs_tab[42];
    {
        int t = threadIdx.x;
        if (t < 42) {
            float th;
            if (t < 24) {
                int tgt = t >> 3, ln = t & 7;
                int base = 3 + 4 * tgt;  // p[base..base+2] controlled, p[base+3] plain
                th = p[base + 3] + 0.5f;
                if (ln & 1) th += p[base];      // ctrl q2
                if (ln & 2) th += p[base + 1];  // ctrl q1
                if (ln & 4) th += p[base + 2];  // ctrl q0
            } else if (t < 33) {
                th = p[t - 9];    // p15..p23
            } else {
                th = p[t - 6];    // p27..p35
            }
            float h = th * 0.5f;
            cs_tab[t] = make_float2(__cosf(h), __sinf(h));
        }
    }
    __syncthreads();

    int gtid = blockIdx.x * blockDim.x + threadIdx.x;
    int e = gtid >> 3;
    int lane = gtid & 7;
    bool live = (e < n);
    int ee = live ? e : 0;
    float xv = x[ee];

    // Hoist the lane-indexed fused-angle pairs (overlaps latency with block 1).
    float2 g3 = cs_tab[lane];
    float2 g4 = cs_tab[8 + lane];
    float2 g5 = cs_tab[16 + lane];

    float st[8];
#pragma unroll
    for (int r = 0; r < 8; ++r) st[r] = 0.0f;
    if (lane == 0) st[0] = 1.0f;

    float c, s;
    auto cs = [&](float th) {  // native v_sin/v_cos
        float h = th * 0.5f;
        s = __sinf(h);
        c = __cosf(h);
    };
    auto tab = [&](int k) {
        float2 v = cs_tab[k];
        c = v.x;
        s = v.y;
    };

    // -- block 1: encoding + variational fused (targets q0,q1,q2; x-dep) --
    cs(fmaf(xv, 3.0f, p[0])); gate_x<4, 0>(st, lane, c, s);
    cs(fmaf(xv, 9.0f, p[1])); gate_x<2, 0>(st, lane, c, s);
    cs(xv + p[2]);            gate_x<1, 0>(st, lane, c, s);

    // -- fused controlled-rotation blocks onto q3, q4, q5 (per-lane angles) --
    ry_r<4, 0>(st, g3.x, g3.y);
    ry_r<2, 0>(st, g4.x, g4.y);
    ry_r<1, 0>(st, g5.x, g5.y);

    // -- entangling block among q3,q4,q5 (register controls) --
    tab(24); ry_r<2, 4>(st, c, s);  // t4 c3  (p15)
    tab(25); ry_r<1, 4>(st, c, s);  // t5 c3  (p16)
    tab(26); ry_r<4, 2>(st, c, s);  // t3 c4  (p17)
    tab(27); ry_r<1, 2>(st, c, s);  // t5 c4  (p18)
    tab(28); ry_r<4, 1>(st, c, s);  // t3 c5  (p19)
    tab(29); ry_r<2, 1>(st, c, s);  // t4 c5  (p20)
    tab(30); ry_r<4, 0>(st, c, s);  //        (p21)
    tab(31); ry_r<2, 0>(st, c, s);  //        (p22)
    tab(32); ry_r<1, 0>(st, c, s);  //        (p23)

    // -- triply-controlled Y on q0,q1,q2: sector r=7 only.
    // new st[7](lane j) = (-1)^popcount(j) * old st[7](lane j^7); phase i drops.
    {
        float ysign = (__popc(lane) & 1) ? -1.0f : 1.0f;
        st[7] = ysign * lane_perm<7>(st[7]);
    }

    // -- block 2: encoding + variational + RY(-0.5), triple-fused (x-dep) --
    cs(fmaf(xv, 7.0f, p[24]) - 0.5f);  gate_x<4, 0>(st, lane, c, s);
    cs(fmaf(xv, 17.0f, p[25]) - 0.5f); gate_x<2, 0>(st, lane, c, s);
    cs(xv + p[26] - 0.5f);             gate_x<1, 0>(st, lane, c, s);

    // -- entangling block among q0,q1,q2 (lane controls) --
    tab(33); gate_x<2, 4>(st, lane, c, s);  // t1 c0  (p27)
    tab(34); gate_x<1, 4>(st, lane, c, s);  // t2 c0  (p28)
    tab(35); gate_x<4, 2>(st, lane, c, s);  // t0 c1  (p29)
    tab(36); gate_x<1, 2>(st, lane, c, s);  // t2 c1  (p30)
    tab(37); gate_x<4, 1>(st, lane, c, s);  // t0 c2  (p31)
    tab(38); gate_x<2, 1>(st, lane, c, s);  // t1 c2  (p32)
    tab(39); gate_x<4, 0>(st, lane, c, s);  //        (p33)
    tab(40); gate_x<2, 0>(st, lane, c, s);  //        (p34)
    tab(41); gate_x<1, 0>(st, lane, c, s);  //        (p35)

    // p000 = lane 0's sum of squares; p111 = lane 7's. Exchange via xor7 DPP.
    float psum = 0.0f;
#pragma unroll
    for (int r = 0; r < 8; ++r) psum = fmaf(st[r], st[r], psum);
    float other = lane_perm<7>(psum);  // lane0 <- lane7 (= p111)
    if (live && lane == 0) out[e] = (other - psum) * 2.0f;
}

extern "C" void kernel_launch(void* const* d_in, const int* in_sizes, int n_in,
                              void* d_out, int out_size, void* d_ws, size_t ws_size,
                              hipStream_t stream) {
    const float* x = (const float*)d_in[0];
    const float* p = (const float*)d_in[1];
    float* out = (float*)d_out;
    int n = in_sizes[0];
    long long threads = (long long)n * 8;
    int block = 256;
    int grid = (int)((threads + block - 1) / block);
    pnn_kernel<<<grid, block, 0, stream>>>(x, p, out, n);
}